// Round 5
// baseline (241.979 us; speedup 1.0000x reference)
//
#include <hip/hip_runtime.h>
#include <hip/hip_bf16.h>
#include <cstddef>
#include <cstdint>

// Problem constants (fixed by reference)
#define BATCH   2
#define S_LEN   2048
#define D_MODEL 1024
#define NH      16
#define HD      64
#define MAXD    1024

// logits = scores*(1/sqrt(64)) + (scores + rel_bias)*64^-0.25
//        = scores*0.47855339 + rel_bias*0.35355339
#define SCORE_SCALE 0.47855339059327373f
#define BIAS_SCALE  0.35355339059327373f
#define FIXM 8.0f
#define LOG2E 1.4426950408889634f

typedef __attribute__((ext_vector_type(8))) short bf16x8;
typedef __attribute__((ext_vector_type(4))) short bf16x4;
typedef __attribute__((ext_vector_type(4))) float f32x4;

static __device__ __forceinline__ unsigned short f2bf(float f) {
    __hip_bfloat16 h = __float2bfloat16(f);
    return *reinterpret_cast<unsigned short*>(&h);
}

#define GLDS(gp, lp) __builtin_amdgcn_global_load_lds( \
    (const __attribute__((address_space(1))) void*)(gp), \
    (__attribute__((address_space(3))) void*)(lp), 16, 0, 0)

// ---------------------------------------------------------------------------
// prep: one launch for (a) x fp32->bf16, (b) 4 weight transpose+converts,
// (c) per-head bias table pb_t[h][rel+2047] with clamp/scales/log2e folded.
// ---------------------------------------------------------------------------
__global__ __launch_bounds__(256) void prep(
    const float* __restrict__ x,
    const float* __restrict__ Wq, const float* __restrict__ Wk,
    const float* __restrict__ Wv, const float* __restrict__ Wo,
    const float* __restrict__ pos_bias,
    unsigned short* __restrict__ xb, unsigned short* __restrict__ Wqkvt,
    unsigned short* __restrict__ Wot,
    float* __restrict__ pb_t)
{
    __shared__ float t[32][33];
    const int bx = blockIdx.x, tid = threadIdx.x;

    if (bx < 2048) {                       // ---- x convert
        const size_t i = ((size_t)bx * 256 + tid) * 8;
        const float4 a = *(const float4*)(x + i);
        const float4 b = *(const float4*)(x + i + 4);
        unsigned short u[8] = {f2bf(a.x), f2bf(a.y), f2bf(a.z), f2bf(a.w),
                               f2bf(b.x), f2bf(b.y), f2bf(b.z), f2bf(b.w)};
        *(uint4*)(xb + i) = *(const uint4*)u;
    } else if (bx < 6144) {                // ---- weight transpose+convert
        const int bx2 = bx - 2048;
        const int z = bx2 >> 10, inner = bx2 & 1023;
        const int gx = inner & 31, gy = inner >> 5;
        const float* W = (z == 0) ? Wq : (z == 1) ? Wk : (z == 2) ? Wv : Wo;
        unsigned short* hi = (z < 3) ? Wqkvt + (size_t)z * 1024 * 1024 : Wot;
        const int bxx = gx * 32, byy = gy * 32;
        const int tx = tid & 31, ty = tid >> 5;
        #pragma unroll
        for (int i = 0; i < 4; i++)
            t[ty + 8 * i][tx] = W[(size_t)(byy + ty + 8 * i) * 1024 + bxx + tx];
        __syncthreads();
        #pragma unroll
        for (int i = 0; i < 4; i++) {
            const float v = t[tx][ty + 8 * i];
            const size_t o = (size_t)(bxx + ty + 8 * i) * 1024 + byy + tx;
            hi[o] = f2bf(v);
        }
    } else {                               // ---- bias table, 16 heads x 4096
        const int o0 = (bx - 6144) * 1024 + tid * 4;
        float v[4];
        #pragma unroll
        for (int j = 0; j < 4; j++) {
            const int o = o0 + j;
            const int hh = o >> 12, ii = o & 4095;
            int rel = ii - 2047;
            rel = min(max(rel, -(MAXD - 1)), MAXD - 1);
            v[j] = (BIAS_SCALE * pos_bias[(size_t)(rel + MAXD - 1) * NH + hh] - FIXM) * LOG2E;
        }
        *(float4*)&pb_t[o0] = *(const float4*)v;
    }
}

// ---------------------------------------------------------------------------
// Fused QKV GEMM: C[4096,3072] = xb @ Wqkvt^T. 128x128 tile, BK=64.
// BK 32->64 halves barrier-drain count; XOR-swizzled LDS (chunk ^ (row&7))
// removes the 8-way read bank conflict of the linear layout (write side stays
// GLDS-linear with pre-swizzled global source, m173 pattern); bijective XCD
// swizzle clusters same-A-panel tiles per XCD L2 (T1).
// Col region 0->Q [B,S,D] (+bq), 1->K [B,S,D], 2->V^T [B,H,HD,S] (+bv, packed).
// ---------------------------------------------------------------------------
#define GBM 128
#define GBN 128
#define GBK 64

__global__ __launch_bounds__(256) void gemm_qkv(
    const unsigned short* __restrict__ A, const unsigned short* __restrict__ Bt,
    const float* __restrict__ bq, const float* __restrict__ bv,
    unsigned short* __restrict__ Cout)
{
    const int K = 1024;
    __shared__ __align__(16) unsigned short As[GBM][GBK];   // 16 KB
    __shared__ __align__(16) unsigned short Bs[GBN][GBK];   // 16 KB

    const int tid = threadIdx.x;
    const int wave = tid >> 6, lane = tid & 63;
    const int quad = lane >> 4, cl = lane & 15;
    const int wm = (wave & 1) * 64, wn = (wave >> 1) * 64;

    // XCD-bijective block swizzle (nwg = 24*32 = 768, 768 % 8 == 0)
    const int gx = gridDim.x;                       // 24
    const int nwg = gx * gridDim.y;                 // 768
    const int cpx = nwg >> 3;                       // 96
    int lin = blockIdx.y * gx + blockIdx.x;
    lin = (lin & 7) * cpx + (lin >> 3);
    const int bn = (lin % gx) * GBN;
    const int bm = (lin / gx) * GBM;

    // Staging: slot s = i*256 + tid -> row = i*32 + (tid>>3),
    // global chunk = (tid&7) ^ (row&7), LDS stays linear (GLDS).
    const int r0 = tid >> 3;
    const int c0 = ((tid & 7) ^ (r0 & 7)) * 8;
    const unsigned short* aS = A  + (size_t)(bm + r0) * K + c0;
    const unsigned short* bS = Bt + (size_t)(bn + r0) * K + c0;
    unsigned short* aD = &As[0][0] + wave * 512;    // wave-uniform LDS bases
    unsigned short* bD = &Bs[0][0] + wave * 512;
    const int ksw = cl & 7;                         // read-side swizzle key

    f32x4 acc[4][4];
    #pragma unroll
    for (int mi = 0; mi < 4; mi++)
        #pragma unroll
        for (int ni = 0; ni < 4; ni++)
            #pragma unroll
            for (int r = 0; r < 4; r++) acc[mi][ni][r] = 0.f;

    for (int k0 = 0; k0 < K; k0 += GBK) {
        __syncthreads();
        GLDS(aS,                  aD);
        GLDS(aS + (size_t)32 * K, aD + 2048);
        GLDS(aS + (size_t)64 * K, aD + 4096);
        GLDS(aS + (size_t)96 * K, aD + 6144);
        GLDS(bS,                  bD);
        GLDS(bS + (size_t)32 * K, bD + 2048);
        GLDS(bS + (size_t)64 * K, bD + 4096);
        GLDS(bS + (size_t)96 * K, bD + 6144);
        aS += GBK; bS += GBK;
        __syncthreads();

        #pragma unroll
        for (int kk = 0; kk < 2; kk++) {
            bf16x8 af[4], bf[4];
            #pragma unroll
            for (int mi = 0; mi < 4; mi++)
                af[mi] = *(const bf16x8*)&As[wm + mi * 16 + cl][((kk * 4 + quad) ^ ksw) * 8];
            #pragma unroll
            for (int ni = 0; ni < 4; ni++)
                bf[ni] = *(const bf16x8*)&Bs[wn + ni * 16 + cl][((kk * 4 + quad) ^ ksw) * 8];
            #pragma unroll
            for (int mi = 0; mi < 4; mi++)
                #pragma unroll
                for (int ni = 0; ni < 4; ni++)
                    acc[mi][ni] = __builtin_amdgcn_mfma_f32_16x16x32_bf16(
                        af[mi], bf[ni], acc[mi][ni], 0, 0, 0);
        }
    }

    #pragma unroll
    for (int ni = 0; ni < 4; ni++) {
        const int coln = bn + wn + ni * 16 + cl;
        const int region = coln >> 10, c = coln & 1023;
        const float bs = (region == 0) ? bq[c] : (region == 2) ? bv[c] : 0.f;
        #pragma unroll
        for (int mi = 0; mi < 4; mi++) {
            const int row0 = bm + wm + mi * 16 + quad * 4;
            if (region == 2) {
                const int hh = c >> 6, d = c & 63;
                const int bb = row0 >> 11, s0 = row0 & 2047;
                unsigned short u[4];
                #pragma unroll
                for (int r = 0; r < 4; r++) u[r] = f2bf(acc[mi][ni][r] + bs);
                unsigned short* dst = Cout + (size_t)8 * 1024 * 1024
                    + (((size_t)bb * NH + hh) * HD + d) * S_LEN + s0;
                *(uint2*)dst = *(const uint2*)u;
            } else {
                unsigned short* dst = Cout + (size_t)region * 4 * 1024 * 1024;
                #pragma unroll
                for (int r = 0; r < 4; r++)
                    dst[(size_t)(row0 + r) * 1024 + c] = f2bf(acc[mi][ni][r] + bs);
            }
        }
    }
}

// ---------------------------------------------------------------------------
// MFMA flash attention v9: v8 (key-split, TQB=128, 512 thr, dbuf GLDS) plus
// T5 s_setprio(1/0) around the pure-MFMA QK and PV clusters -- proven +4-7%
// on attention when waves have role diversity (m191).
// ---------------------------------------------------------------------------
#define TQB 128
#define TKB 64

__global__ __launch_bounds__(512, 4) void attn_mfma(
    const unsigned short* __restrict__ Q, const unsigned short* __restrict__ K,
    const unsigned short* __restrict__ VT, const float* __restrict__ pb_t,
    unsigned short* __restrict__ O)
{
    const int qt = blockIdx.x, h = blockIdx.y, b = blockIdx.z;
    const int tid  = threadIdx.x;
    const int wave = tid >> 6, lane = tid & 63;
    const int g = wave >> 2, w4 = wave & 3;    // key-split group, wave-in-group
    const int quad = lane >> 4, col = lane & 15;
    const int qbase = qt * TQB;
    const int qw = qbase + w4 * 32;            // wave owns q rows qw..qw+31

    // [g][p] { K: 8192 B | V: 8192 B }; reused as merge buffer afterwards.
    __shared__ __align__(16) unsigned char smem[65536];
    unsigned char* const base_g = smem + g * 32768;

    bf16x8 qf[2][2];
    #pragma unroll
    for (int f = 0; f < 2; f++) {
        const unsigned short* qp =
            &Q[((size_t)(b * S_LEN) + qw + f * 16 + col) * D_MODEL + h * HD + quad * 8];
        qf[f][0] = *(const bf16x8*)qp;
        qf[f][1] = *(const bf16x8*)(qp + 32);
    }

    f32x4 accO[2][4];
    #pragma unroll
    for (int f = 0; f < 2; f++)
        #pragma unroll
        for (int nb = 0; nb < 4; nb++)
            #pragma unroll
            for (int r = 0; r < 4; r++) accO[f][nb][r] = 0.f;
    f32x4 accL[2];
    #pragma unroll
    for (int f = 0; f < 2; f++)
        #pragma unroll
        for (int r = 0; r < 4; r++) accL[f][r] = 0.f;
    const bf16x4 vone = {(short)16256, (short)16256, (short)16256, (short)16256}; // bf16 1.0

    // GLDS staging within the group: 256 threads stage 512 slots per matrix.
    // Slot s = i*256 + tg holds (row = s>>3, chunk (s&7)^(row&7)).
    const int tg = tid & 255;
    const int s0 = tg, s1 = 256 + tg;
    const int kr0 = s0 >> 3, kj0 = (s0 & 7) ^ (kr0 & 7);
    const int kr1 = s1 >> 3, kj1 = (s1 & 7) ^ (kr1 & 7);
    const unsigned short* kS0 =
        K + ((size_t)(b * S_LEN) + g * 1024 + kr0) * D_MODEL + h * HD + kj0 * 8;
    const unsigned short* kS1 =
        K + ((size_t)(b * S_LEN) + g * 1024 + kr1) * D_MODEL + h * HD + kj1 * 8;
    const size_t vbase = ((size_t)(b * NH + h) * HD) * S_LEN;
    const unsigned short* vS0 = VT + vbase + (size_t)kr0 * S_LEN + g * 1024 + kj0 * 8;
    const unsigned short* vS1 = VT + vbase + (size_t)kr1 * S_LEN + g * 1024 + kj1 * 8;
    // LDS dests (ushort elements): K at base_g + p*16384B, V at +8192B.
    unsigned short* kD = (unsigned short*)base_g + w4 * 512;
    unsigned short* vD = (unsigned short*)(base_g + 8192) + w4 * 512;

    const float* pbh = pb_t + h * 4096;
    const float* pb_lane = pbh + (qw + col - quad * 4 - g * 1024 + 2047);
    const float SC2 = SCORE_SCALE * LOG2E;
    const int jsw = col & 7;   // swizzle key for this lane's rows

    // ---- prologue: stage this group's tile 0 into buffer 0
    GLDS(kS0, kD); GLDS(kS1, kD + 2048);
    GLDS(vS0, vD); GLDS(vS1, vD + 2048);
    kS0 += (size_t)TKB * D_MODEL; kS1 += (size_t)TKB * D_MODEL;
    vS0 += TKB; vS1 += TKB;
    __syncthreads();   // drains prologue GLDS -> buffer 0 ready (both groups)

    const int NT = 1024 / TKB;   // 16 tiles per group

// One K/V tile with literal dbuf parity P. Bias single-buffered: issued at
// tile start, consumed after QK^T (latency hidden under 16 MFMAs; L2-hot).
#define ATT_TILE(T, P)                                                        \
  {                                                                           \
    if ((T) != NT - 1) {                                                      \
      GLDS(kS0, kD + ((P) ^ 1) * 8192); GLDS(kS1, kD + ((P) ^ 1) * 8192 + 2048); \
      GLDS(vS0, vD + ((P) ^ 1) * 8192); GLDS(vS1, vD + ((P) ^ 1) * 8192 + 2048); \
      kS0 += (size_t)TKB * D_MODEL; kS1 += (size_t)TKB * D_MODEL;             \
      vS0 += TKB; vS1 += TKB;                                                 \
    }                                                                         \
    float bias_c[2][16];                                                      \
    _Pragma("unroll")                                                         \
    for (int f = 0; f < 2; f++)                                               \
      _Pragma("unroll")                                                       \
      for (int nb = 0; nb < 4; nb++)                                          \
        _Pragma("unroll")                                                     \
        for (int r = 0; r < 4; r++)                                           \
          bias_c[f][nb * 4 + r] = pb_lane[f * 16 - (nb * 16 + r)];            \
    pb_lane -= TKB;                                                           \
    const unsigned short* Kp = (const unsigned short*)(base_g + (P) * 16384); \
    const unsigned short* Vp = (const unsigned short*)(base_g + (P) * 16384 + 8192); \
    f32x4 accS[2][4];                                                         \
    _Pragma("unroll")                                                         \
    for (int f = 0; f < 2; f++)                                               \
      _Pragma("unroll")                                                       \
      for (int nb = 0; nb < 4; nb++)                                          \
        _Pragma("unroll")                                                     \
        for (int r = 0; r < 4; r++) accS[f][nb][r] = 0.f;                     \
    __builtin_amdgcn_s_setprio(1);                                            \
    _Pragma("unroll")                                                         \
    for (int kk = 0; kk < 2; kk++)                                            \
      _Pragma("unroll")                                                       \
      for (int nb = 0; nb < 4; nb++) {                                        \
        const bf16x8 kf = *(const bf16x8*)                                    \
            &Kp[(nb * 16 + col) * 64 + (((kk * 4 + quad) ^ jsw) * 8)];        \
        accS[0][nb] = __builtin_amdgcn_mfma_f32_16x16x32_bf16(                \
            kf, qf[0][kk], accS[0][nb], 0, 0, 0);                             \
        accS[1][nb] = __builtin_amdgcn_mfma_f32_16x16x32_bf16(                \
            kf, qf[1][kk], accS[1][nb], 0, 0, 0);                             \
      }                                                                       \
    __builtin_amdgcn_s_setprio(0);                                            \
    bf16x4 pf[2][4];                                                          \
    _Pragma("unroll")                                                         \
    for (int f = 0; f < 2; f++)                                               \
      _Pragma("unroll")                                                       \
      for (int nb = 0; nb < 4; nb++) {                                        \
        float pr[4];                                                          \
        _Pragma("unroll")                                                     \
        for (int r = 0; r < 4; r++)                                           \
          pr[r] = __builtin_amdgcn_exp2f(                                     \
              fmaf(accS[f][nb][r], SC2, bias_c[f][nb * 4 + r]));              \
        const __hip_bfloat162 h0 = __float22bfloat162_rn(make_float2(pr[0], pr[1])); \
        const __hip_bfloat162 h1 = __float22bfloat162_rn(make_float2(pr[2], pr[3])); \
        uint2 w;                                                              \
        w.x = *(const unsigned int*)&h0;                                      \
        w.y = *(const unsigned int*)&h1;                                      \
        union { uint2 u; bf16x4 v; } cv;                                      \
        cv.u = w;                                                             \
        pf[f][nb] = cv.v;                                                     \
        accL[f] = __builtin_amdgcn_mfma_f32_16x16x16bf16_1k(                  \
            vone, pf[f][nb], accL[f], 0, 0, 0);                               \
      }                                                                       \
    __builtin_amdgcn_s_setprio(1);                                            \
    _Pragma("unroll")                                                         \
    for (int s = 0; s < 4; s++)                                               \
      _Pragma("unroll")                                                       \
      for (int nb = 0; nb < 4; nb++) {                                        \
        const bf16x4 vf = *(const bf16x4*)                                    \
            &Vp[(nb * 16 + col) * 64 + (((2 * s + (quad >> 1)) ^ jsw) * 8) + (quad & 1) * 4]; \
        accO[0][nb] = __builtin_amdgcn_mfma_f32_16x16x16bf16_1k(              \
            vf, pf[0][s], accO[0][nb], 0, 0, 0);                              \
        accO[1][nb] = __builtin_amdgcn_mfma_f32_16x16x16bf16_1k(              \
            vf, pf[1][s], accO[1][nb], 0, 0, 0);                              \
      }                                                                       \
    __builtin_amdgcn_s_setprio(0);                                            \
    __syncthreads();                                                          \
  }

    for (int t = 0; t < NT; t += 2) {
        ATT_TILE(t,     0);
        ATT_TILE(t + 1, 1);
    }
#undef ATT_TILE

    // ---- key-split merge via LDS (K/V buffers are dead; last barrier done).
    // 256 lanes/group x 34 floats: [0..31] accO, [32..33] accL. 34.8 KB < 64 KB.
    float* const Mo = (float*)smem;
    const int idx = (w4 * 64 + lane) * 34;
    if (g == 1) {
        #pragma unroll
        for (int f = 0; f < 2; f++) {
            #pragma unroll
            for (int nb = 0; nb < 4; nb++)
                #pragma unroll
                for (int r = 0; r < 4; r++)
                    Mo[idx + f * 16 + nb * 4 + r] = accO[f][nb][r];
            Mo[idx + 32 + f] = accL[f][0];
        }
    }
    __syncthreads();
    if (g == 0) {
        // accL rows all identical = this group's l for q=col (MFMA-summed)
        #pragma unroll
        for (int f = 0; f < 2; f++) {
            const float inv = 1.0f / (accL[f][0] + Mo[idx + 32 + f]);
            const size_t row = (size_t)(b * S_LEN) + qw + f * 16 + col;
            #pragma unroll
            for (int nb = 0; nb < 4; nb++) {
                unsigned short u[4];
                #pragma unroll
                for (int r = 0; r < 4; r++)
                    u[r] = f2bf((accO[f][nb][r] + Mo[idx + f * 16 + nb * 4 + r]) * inv);
                *(uint2*)&O[row * D_MODEL + h * HD + nb * 16 + quad * 4] = *(const uint2*)u;
            }
        }
    }
}

// ---------------------------------------------------------------------------
// Output projection: out[4096,1024] = Ab @ Wot^T + bo, fp32 out.
// 64x128 tile (512 blocks), BK=64, XOR-swizzled LDS + XCD swizzle (as qkv).
// ---------------------------------------------------------------------------
#define OBM 64
#define OBN 128
#define OBK 64

__global__ __launch_bounds__(256) void gemm_out(
    const unsigned short* __restrict__ A, const unsigned short* __restrict__ Bt,
    const float* __restrict__ bias, float* __restrict__ Cout)
{
    const int N = 1024, Kd = 1024;
    __shared__ __align__(16) unsigned short As[OBM][OBK];   // 8 KB
    __shared__ __align__(16) unsigned short Bs[OBN][OBK];   // 16 KB

    const int tid = threadIdx.x;
    const int wave = tid >> 6, lane = tid & 63;
    const int quad = lane >> 4, cl = lane & 15;
    const int wm = (wave & 1) * 32, wn = (wave >> 1) * 64;

    // XCD-bijective block swizzle (nwg = 8*64 = 512, 512 % 8 == 0)
    const int gx = gridDim.x;                       // 8
    const int nwg = gx * gridDim.y;                 // 512
    const int cpx = nwg >> 3;                       // 64
    int lin = blockIdx.y * gx + blockIdx.x;
    lin = (lin & 7) * cpx + (lin >> 3);
    const int bn = (lin % gx) * OBN;
    const int bm = (lin / gx) * OBM;

    const int r0 = tid >> 3;
    const int c0 = ((tid & 7) ^ (r0 & 7)) * 8;
    const unsigned short* aS = A  + (size_t)(bm + r0) * Kd + c0;
    const unsigned short* bS = Bt + (size_t)(bn + r0) * Kd + c0;
    unsigned short* aD = &As[0][0] + wave * 512;
    unsigned short* bD = &Bs[0][0] + wave * 512;
    const int ksw = cl & 7;

    f32x4 acc[2][4];
    #pragma unroll
    for (int mi = 0; mi < 2; mi++)
        #pragma unroll
        for (int ni = 0; ni < 4; ni++)
            #pragma unroll
            for (int r = 0; r < 4; r++) acc[mi][ni][r] = 0.f;

    for (int k0 = 0; k0 < Kd; k0 += OBK) {
        __syncthreads();
        GLDS(aS,                   aD);
        GLDS(aS + (size_t)32 * Kd, aD + 2048);
        GLDS(bS,                   bD);
        GLDS(bS + (size_t)32 * Kd, bD + 2048);
        GLDS(bS + (size_t)64 * Kd, bD + 4096);
        GLDS(bS + (size_t)96 * Kd, bD + 6144);
        aS += OBK; bS += OBK;
        __syncthreads();

        #pragma unroll
        for (int kk = 0; kk < 2; kk++) {
            bf16x8 af[2], bh[4];
            #pragma unroll
            for (int mi = 0; mi < 2; mi++)
                af[mi] = *(const bf16x8*)&As[wm + mi * 16 + cl][((kk * 4 + quad) ^ ksw) * 8];
            #pragma unroll
            for (int ni = 0; ni < 4; ni++)
                bh[ni] = *(const bf16x8*)&Bs[wn + ni * 16 + cl][((kk * 4 + quad) ^ ksw) * 8];
            #pragma unroll
            for (int mi = 0; mi < 2; mi++)
                #pragma unroll
                for (int ni = 0; ni < 4; ni++)
                    acc[mi][ni] = __builtin_amdgcn_mfma_f32_16x16x32_bf16(
                        af[mi], bh[ni], acc[mi][ni], 0, 0, 0);
        }
    }

    #pragma unroll
    for (int ni = 0; ni < 4; ni++) {
        const int coln = bn + wn + ni * 16 + cl;
        const float bs = bias[coln];
        #pragma unroll
        for (int mi = 0; mi < 2; mi++) {
            const int row0 = bm + wm + mi * 16 + quad * 4;
            #pragma unroll
            for (int r = 0; r < 4; r++)
                Cout[(size_t)(row0 + r) * N + coln] = acc[mi][ni][r] + bs;
        }
    }
}

// ---------------------------------------------------------------------------
extern "C" void kernel_launch(void* const* d_in, const int* in_sizes, int n_in,
                              void* d_out, int out_size, void* d_ws, size_t ws_size,
                              hipStream_t stream)
{
    const float* x        = (const float*)d_in[0];
    const float* Wq       = (const float*)d_in[1];
    const float* bq       = (const float*)d_in[2];
    const float* Wk       = (const float*)d_in[3];
    const float* Wv       = (const float*)d_in[4];
    const float* bv       = (const float*)d_in[5];
    const float* Wo       = (const float*)d_in[6];
    const float* bo       = (const float*)d_in[7];
    const float* pos_bias = (const float*)d_in[8];
    float* out = (float*)d_out;

    const size_t ELEMS  = (size_t)BATCH * S_LEN * D_MODEL;  // 4 Mi
    const size_t WELEMS = (size_t)D_MODEL * D_MODEL;        // 1 Mi
    unsigned short* xb     = (unsigned short*)d_ws;
    unsigned short* Wqkvt  = xb + ELEMS;                    // [3072][1024]
    unsigned short* Wot    = Wqkvt + 3 * WELEMS;
    unsigned short* QKV    = Wot + WELEMS;                  // Qb | Kb | VTb
    unsigned short* Qb     = QKV;
    unsigned short* Kb     = Qb + ELEMS;
    unsigned short* VTb    = Kb + ELEMS;                    // [B,H,HD,S]
    unsigned short* Ab     = VTb + ELEMS;                   // attn out bf16 [B,S,D]
    float* pb_t            = (float*)(Ab + ELEMS);          // [NH][4096]

    prep<<<6208, 256, 0, stream>>>(x, Wq, Wk, Wv, Wo, pos_bias,
                                   xb, Wqkvt, Wot, pb_t);

    gemm_qkv<<<dim3(3072 / GBN, 4096 / GBM), 256, 0, stream>>>(
        xb, Wqkvt, bq, bv, QKV);

    attn_mfma<<<dim3(S_LEN / TQB, NH, BATCH), 512, 0, stream>>>(
        Qb, Kb, VTb, pb_t, Ab);

    gemm_out<<<dim3(1024 / OBN, 4096 / OBM), 256, 0, stream>>>(
        Ab, Wot, bo, out);
}

// Round 6
// 197.555 us; speedup vs baseline: 1.2249x; 1.2249x over previous
//
#include <hip/hip_runtime.h>
#include <hip/hip_bf16.h>
#include <cstddef>
#include <cstdint>

// Problem constants (fixed by reference)
#define BATCH   2
#define S_LEN   2048
#define D_MODEL 1024
#define NH      16
#define HD      64
#define MAXD    1024

// logits = scores*(1/sqrt(64)) + (scores + rel_bias)*64^-0.25
//        = scores*0.47855339 + rel_bias*0.35355339
#define SCORE_SCALE 0.47855339059327373f
#define BIAS_SCALE  0.35355339059327373f
#define FIXM 8.0f
#define LOG2E 1.4426950408889634f

typedef __attribute__((ext_vector_type(8))) short bf16x8;
typedef __attribute__((ext_vector_type(4))) short bf16x4;
typedef __attribute__((ext_vector_type(4))) float f32x4;

static __device__ __forceinline__ unsigned short f2bf(float f) {
    __hip_bfloat16 h = __float2bfloat16(f);
    return *reinterpret_cast<unsigned short*>(&h);
}

#define GLDS(gp, lp) __builtin_amdgcn_global_load_lds( \
    (const __attribute__((address_space(1))) void*)(gp), \
    (__attribute__((address_space(3))) void*)(lp), 16, 0, 0)

// ---------------------------------------------------------------------------
// prep: one launch for (a) x fp32->bf16, (b) 4 weight transpose+converts,
// (c) per-head bias table pb_t[h][rel+2047] with clamp/scales/log2e folded.
// ---------------------------------------------------------------------------
__global__ __launch_bounds__(256) void prep(
    const float* __restrict__ x,
    const float* __restrict__ Wq, const float* __restrict__ Wk,
    const float* __restrict__ Wv, const float* __restrict__ Wo,
    const float* __restrict__ pos_bias,
    unsigned short* __restrict__ xb, unsigned short* __restrict__ Wqkvt,
    unsigned short* __restrict__ Wot,
    float* __restrict__ pb_t)
{
    __shared__ float t[32][33];
    const int bx = blockIdx.x, tid = threadIdx.x;

    if (bx < 2048) {                       // ---- x convert
        const size_t i = ((size_t)bx * 256 + tid) * 8;
        const float4 a = *(const float4*)(x + i);
        const float4 b = *(const float4*)(x + i + 4);
        unsigned short u[8] = {f2bf(a.x), f2bf(a.y), f2bf(a.z), f2bf(a.w),
                               f2bf(b.x), f2bf(b.y), f2bf(b.z), f2bf(b.w)};
        *(uint4*)(xb + i) = *(const uint4*)u;
    } else if (bx < 6144) {                // ---- weight transpose+convert
        const int bx2 = bx - 2048;
        const int z = bx2 >> 10, inner = bx2 & 1023;
        const int gx = inner & 31, gy = inner >> 5;
        const float* W = (z == 0) ? Wq : (z == 1) ? Wk : (z == 2) ? Wv : Wo;
        unsigned short* hi = (z < 3) ? Wqkvt + (size_t)z * 1024 * 1024 : Wot;
        const int bxx = gx * 32, byy = gy * 32;
        const int tx = tid & 31, ty = tid >> 5;
        #pragma unroll
        for (int i = 0; i < 4; i++)
            t[ty + 8 * i][tx] = W[(size_t)(byy + ty + 8 * i) * 1024 + bxx + tx];
        __syncthreads();
        #pragma unroll
        for (int i = 0; i < 4; i++) {
            const float v = t[tx][ty + 8 * i];
            const size_t o = (size_t)(bxx + ty + 8 * i) * 1024 + byy + tx;
            hi[o] = f2bf(v);
        }
    } else {                               // ---- bias table, 16 heads x 4096
        const int o0 = (bx - 6144) * 1024 + tid * 4;
        float v[4];
        #pragma unroll
        for (int j = 0; j < 4; j++) {
            const int o = o0 + j;
            const int hh = o >> 12, ii = o & 4095;
            int rel = ii - 2047;
            rel = min(max(rel, -(MAXD - 1)), MAXD - 1);
            v[j] = (BIAS_SCALE * pos_bias[(size_t)(rel + MAXD - 1) * NH + hh] - FIXM) * LOG2E;
        }
        *(float4*)&pb_t[o0] = *(const float4*)v;
    }
}

// ---------------------------------------------------------------------------
// Fused QKV GEMM: C[4096,3072] = xb @ Wqkvt^T. 128x128 tile, BK=32, m97-style.
// Col region 0->Q [B,S,D] (+bq), 1->K [B,S,D], 2->V^T [B,H,HD,S] (+bv, packed).
// (Reverted to the R3-verified version; R5's BK=64/XCD bundle was neutral on
// the GEMMs and confounded the attn measurement.)
// ---------------------------------------------------------------------------
#define GBM 128
#define GBN 128
#define GBK 32

__global__ __launch_bounds__(256) void gemm_qkv(
    const unsigned short* __restrict__ A, const unsigned short* __restrict__ Bt,
    const float* __restrict__ bq, const float* __restrict__ bv,
    unsigned short* __restrict__ Cout)
{
    const int K = 1024;
    __shared__ __align__(16) unsigned short As[GBM][GBK];
    __shared__ __align__(16) unsigned short Bs[GBN][GBK];

    const int tid = threadIdx.x;
    const int wave = tid >> 6, lane = tid & 63;
    const int quad = lane >> 4, cl = lane & 15;
    const int wm = (wave & 1) * 64, wn = (wave >> 1) * 64;
    const int bm = blockIdx.y * GBM, bn = blockIdx.x * GBN;

    const int sr = wave * 32 + (lane >> 2);
    const int sc = (lane & 3) * 8;
    const unsigned short* aS0 = A  + (size_t)(bm + sr) * K + sc;
    const unsigned short* aS1 = aS0 + (size_t)16 * K;
    const unsigned short* bS0 = Bt + (size_t)(bn + sr) * K + sc;
    const unsigned short* bS1 = bS0 + (size_t)16 * K;
    unsigned short* aD0 = &As[wave * 32][0];
    unsigned short* aD1 = &As[wave * 32 + 16][0];
    unsigned short* bD0 = &Bs[wave * 32][0];
    unsigned short* bD1 = &Bs[wave * 32 + 16][0];

    f32x4 acc[4][4];
    #pragma unroll
    for (int mi = 0; mi < 4; mi++)
        #pragma unroll
        for (int ni = 0; ni < 4; ni++)
            #pragma unroll
            for (int r = 0; r < 4; r++) acc[mi][ni][r] = 0.f;

    for (int k0 = 0; k0 < K; k0 += GBK) {
        __syncthreads();
        GLDS(aS0, aD0); GLDS(aS1, aD1);
        GLDS(bS0, bD0); GLDS(bS1, bD1);
        aS0 += GBK; aS1 += GBK; bS0 += GBK; bS1 += GBK;
        __syncthreads();

        bf16x8 af[4], bf[4];
        #pragma unroll
        for (int mi = 0; mi < 4; mi++)
            af[mi] = *(const bf16x8*)&As[wm + mi * 16 + cl][quad * 8];
        #pragma unroll
        for (int ni = 0; ni < 4; ni++)
            bf[ni] = *(const bf16x8*)&Bs[wn + ni * 16 + cl][quad * 8];
        #pragma unroll
        for (int mi = 0; mi < 4; mi++)
            #pragma unroll
            for (int ni = 0; ni < 4; ni++)
                acc[mi][ni] = __builtin_amdgcn_mfma_f32_16x16x32_bf16(
                    af[mi], bf[ni], acc[mi][ni], 0, 0, 0);
    }

    #pragma unroll
    for (int ni = 0; ni < 4; ni++) {
        const int coln = bn + wn + ni * 16 + cl;
        const int region = coln >> 10, c = coln & 1023;
        const float bs = (region == 0) ? bq[c] : (region == 2) ? bv[c] : 0.f;
        #pragma unroll
        for (int mi = 0; mi < 4; mi++) {
            const int row0 = bm + wm + mi * 16 + quad * 4;
            if (region == 2) {
                const int hh = c >> 6, d = c & 63;
                const int bb = row0 >> 11, s0 = row0 & 2047;
                unsigned short u[4];
                #pragma unroll
                for (int r = 0; r < 4; r++) u[r] = f2bf(acc[mi][ni][r] + bs);
                unsigned short* dst = Cout + (size_t)8 * 1024 * 1024
                    + (((size_t)bb * NH + hh) * HD + d) * S_LEN + s0;
                *(uint2*)dst = *(const uint2*)u;
            } else {
                unsigned short* dst = Cout + (size_t)region * 4 * 1024 * 1024;
                #pragma unroll
                for (int r = 0; r < 4; r++)
                    dst[(size_t)(row0 + r) * 1024 + c] = f2bf(acc[mi][ni][r] + bs);
            }
        }
    }
}

// ---------------------------------------------------------------------------
// MFMA flash attention v10: exactly the R3-verified v8 body (key-split,
// TQB=128, 512 thr, dbuf GLDS, NO setprio) with ONE change: 1D grid with
// lin = qt*32 + (h*2+b), so XCD = lin%8 = (h*2+b)%8 -- all 16 qt-blocks
// sharing one (h,b)'s 512 KB K/V panel land on ONE XCD. Per-XCD K/V
// footprint drops 4 MB (at the L2 cliff; R5's thrash: 170 MB writebacks)
// to 2 MB, making every K/V re-read an intra-XCD L2 hit.
// ---------------------------------------------------------------------------
#define TQB 128
#define TKB 64

__global__ __launch_bounds__(512, 4) void attn_mfma(
    const unsigned short* __restrict__ Q, const unsigned short* __restrict__ K,
    const unsigned short* __restrict__ VT, const float* __restrict__ pb_t,
    unsigned short* __restrict__ O)
{
    // XCD-affinity decode: lin = qt*32 + (h*2+b)
    const int lin = blockIdx.x;
    const int qt = lin >> 5;
    const int hb = lin & 31;
    const int h = hb >> 1, b = hb & 1;

    const int tid  = threadIdx.x;
    const int wave = tid >> 6, lane = tid & 63;
    const int g = wave >> 2, w4 = wave & 3;    // key-split group, wave-in-group
    const int quad = lane >> 4, col = lane & 15;
    const int qbase = qt * TQB;
    const int qw = qbase + w4 * 32;            // wave owns q rows qw..qw+31

    // [g][p] { K: 8192 B | V: 8192 B }; reused as merge buffer afterwards.
    __shared__ __align__(16) unsigned char smem[65536];
    unsigned char* const base_g = smem + g * 32768;

    bf16x8 qf[2][2];
    #pragma unroll
    for (int f = 0; f < 2; f++) {
        const unsigned short* qp =
            &Q[((size_t)(b * S_LEN) + qw + f * 16 + col) * D_MODEL + h * HD + quad * 8];
        qf[f][0] = *(const bf16x8*)qp;
        qf[f][1] = *(const bf16x8*)(qp + 32);
    }

    f32x4 accO[2][4];
    #pragma unroll
    for (int f = 0; f < 2; f++)
        #pragma unroll
        for (int nb = 0; nb < 4; nb++)
            #pragma unroll
            for (int r = 0; r < 4; r++) accO[f][nb][r] = 0.f;
    f32x4 accL[2];
    #pragma unroll
    for (int f = 0; f < 2; f++)
        #pragma unroll
        for (int r = 0; r < 4; r++) accL[f][r] = 0.f;
    const bf16x4 vone = {(short)16256, (short)16256, (short)16256, (short)16256}; // bf16 1.0

    // GLDS staging within the group: 256 threads stage 512 slots per matrix.
    // Slot s = i*256 + tg holds (row = s>>3, chunk (s&7)^(row&7)).
    const int tg = tid & 255;
    const int s0 = tg, s1 = 256 + tg;
    const int kr0 = s0 >> 3, kj0 = (s0 & 7) ^ (kr0 & 7);
    const int kr1 = s1 >> 3, kj1 = (s1 & 7) ^ (kr1 & 7);
    const unsigned short* kS0 =
        K + ((size_t)(b * S_LEN) + g * 1024 + kr0) * D_MODEL + h * HD + kj0 * 8;
    const unsigned short* kS1 =
        K + ((size_t)(b * S_LEN) + g * 1024 + kr1) * D_MODEL + h * HD + kj1 * 8;
    const size_t vbase = ((size_t)(b * NH + h) * HD) * S_LEN;
    const unsigned short* vS0 = VT + vbase + (size_t)kr0 * S_LEN + g * 1024 + kj0 * 8;
    const unsigned short* vS1 = VT + vbase + (size_t)kr1 * S_LEN + g * 1024 + kj1 * 8;
    // LDS dests (ushort elements): K at base_g + p*16384B, V at +8192B.
    unsigned short* kD = (unsigned short*)base_g + w4 * 512;
    unsigned short* vD = (unsigned short*)(base_g + 8192) + w4 * 512;

    const float* pbh = pb_t + h * 4096;
    const float* pb_lane = pbh + (qw + col - quad * 4 - g * 1024 + 2047);
    const float SC2 = SCORE_SCALE * LOG2E;
    const int jsw = col & 7;   // swizzle key for this lane's rows

    // ---- prologue: stage this group's tile 0 into buffer 0
    GLDS(kS0, kD); GLDS(kS1, kD + 2048);
    GLDS(vS0, vD); GLDS(vS1, vD + 2048);
    kS0 += (size_t)TKB * D_MODEL; kS1 += (size_t)TKB * D_MODEL;
    vS0 += TKB; vS1 += TKB;
    __syncthreads();   // drains prologue GLDS -> buffer 0 ready (both groups)

    const int NT = 1024 / TKB;   // 16 tiles per group

// One K/V tile with literal dbuf parity P. Bias single-buffered: issued at
// tile start, consumed after QK^T (latency hidden under 16 MFMAs; L2-hot).
#define ATT_TILE(T, P)                                                        \
  {                                                                           \
    if ((T) != NT - 1) {                                                      \
      GLDS(kS0, kD + ((P) ^ 1) * 8192); GLDS(kS1, kD + ((P) ^ 1) * 8192 + 2048); \
      GLDS(vS0, vD + ((P) ^ 1) * 8192); GLDS(vS1, vD + ((P) ^ 1) * 8192 + 2048); \
      kS0 += (size_t)TKB * D_MODEL; kS1 += (size_t)TKB * D_MODEL;             \
      vS0 += TKB; vS1 += TKB;                                                 \
    }                                                                         \
    float bias_c[2][16];                                                      \
    _Pragma("unroll")                                                         \
    for (int f = 0; f < 2; f++)                                               \
      _Pragma("unroll")                                                       \
      for (int nb = 0; nb < 4; nb++)                                          \
        _Pragma("unroll")                                                     \
        for (int r = 0; r < 4; r++)                                           \
          bias_c[f][nb * 4 + r] = pb_lane[f * 16 - (nb * 16 + r)];            \
    pb_lane -= TKB;                                                           \
    const unsigned short* Kp = (const unsigned short*)(base_g + (P) * 16384); \
    const unsigned short* Vp = (const unsigned short*)(base_g + (P) * 16384 + 8192); \
    f32x4 accS[2][4];                                                         \
    _Pragma("unroll")                                                         \
    for (int f = 0; f < 2; f++)                                               \
      _Pragma("unroll")                                                       \
      for (int nb = 0; nb < 4; nb++)                                          \
        _Pragma("unroll")                                                     \
        for (int r = 0; r < 4; r++) accS[f][nb][r] = 0.f;                     \
    _Pragma("unroll")                                                         \
    for (int kk = 0; kk < 2; kk++)                                            \
      _Pragma("unroll")                                                       \
      for (int nb = 0; nb < 4; nb++) {                                        \
        const bf16x8 kf = *(const bf16x8*)                                    \
            &Kp[(nb * 16 + col) * 64 + (((kk * 4 + quad) ^ jsw) * 8)];        \
        accS[0][nb] = __builtin_amdgcn_mfma_f32_16x16x32_bf16(                \
            kf, qf[0][kk], accS[0][nb], 0, 0, 0);                             \
        accS[1][nb] = __builtin_amdgcn_mfma_f32_16x16x32_bf16(                \
            kf, qf[1][kk], accS[1][nb], 0, 0, 0);                             \
      }                                                                       \
    bf16x4 pf[2][4];                                                          \
    _Pragma("unroll")                                                         \
    for (int f = 0; f < 2; f++)                                               \
      _Pragma("unroll")                                                       \
      for (int nb = 0; nb < 4; nb++) {                                        \
        float pr[4];                                                          \
        _Pragma("unroll")                                                     \
        for (int r = 0; r < 4; r++)                                           \
          pr[r] = __builtin_amdgcn_exp2f(                                     \
              fmaf(accS[f][nb][r], SC2, bias_c[f][nb * 4 + r]));              \
        const __hip_bfloat162 h0 = __float22bfloat162_rn(make_float2(pr[0], pr[1])); \
        const __hip_bfloat162 h1 = __float22bfloat162_rn(make_float2(pr[2], pr[3])); \
        uint2 w;                                                              \
        w.x = *(const unsigned int*)&h0;                                      \
        w.y = *(const unsigned int*)&h1;                                      \
        union { uint2 u; bf16x4 v; } cv;                                      \
        cv.u = w;                                                             \
        pf[f][nb] = cv.v;                                                     \
        accL[f] = __builtin_amdgcn_mfma_f32_16x16x16bf16_1k(                  \
            vone, pf[f][nb], accL[f], 0, 0, 0);                               \
      }                                                                       \
    _Pragma("unroll")                                                         \
    for (int s = 0; s < 4; s++)                                               \
      _Pragma("unroll")                                                       \
      for (int nb = 0; nb < 4; nb++) {                                        \
        const bf16x4 vf = *(const bf16x4*)                                    \
            &Vp[(nb * 16 + col) * 64 + (((2 * s + (quad >> 1)) ^ jsw) * 8) + (quad & 1) * 4]; \
        accO[0][nb] = __builtin_amdgcn_mfma_f32_16x16x16bf16_1k(              \
            vf, pf[0][s], accO[0][nb], 0, 0, 0);                              \
        accO[1][nb] = __builtin_amdgcn_mfma_f32_16x16x16bf16_1k(              \
            vf, pf[1][s], accO[1][nb], 0, 0, 0);                              \
      }                                                                       \
    __syncthreads();                                                          \
  }

    for (int t = 0; t < NT; t += 2) {
        ATT_TILE(t,     0);
        ATT_TILE(t + 1, 1);
    }
#undef ATT_TILE

    // ---- key-split merge via LDS (K/V buffers are dead; last barrier done).
    // 256 lanes/group x 34 floats: [0..31] accO, [32..33] accL. 34.8 KB < 64 KB.
    float* const Mo = (float*)smem;
    const int idx = (w4 * 64 + lane) * 34;
    if (g == 1) {
        #pragma unroll
        for (int f = 0; f < 2; f++) {
            #pragma unroll
            for (int nb = 0; nb < 4; nb++)
                #pragma unroll
                for (int r = 0; r < 4; r++)
                    Mo[idx + f * 16 + nb * 4 + r] = accO[f][nb][r];
            Mo[idx + 32 + f] = accL[f][0];
        }
    }
    __syncthreads();
    if (g == 0) {
        // accL rows all identical = this group's l for q=col (MFMA-summed)
        #pragma unroll
        for (int f = 0; f < 2; f++) {
            const float inv = 1.0f / (accL[f][0] + Mo[idx + 32 + f]);
            const size_t row = (size_t)(b * S_LEN) + qw + f * 16 + col;
            #pragma unroll
            for (int nb = 0; nb < 4; nb++) {
                unsigned short u[4];
                #pragma unroll
                for (int r = 0; r < 4; r++)
                    u[r] = f2bf((accO[f][nb][r] + Mo[idx + f * 16 + nb * 4 + r]) * inv);
                *(uint2*)&O[row * D_MODEL + h * HD + nb * 16 + quad * 4] = *(const uint2*)u;
            }
        }
    }
}

// ---------------------------------------------------------------------------
// Output projection: out[4096,1024] = Ab @ Wot^T + bo, fp32 out.
// 64x128 tile (512 blocks), BK=32, single bf16 B. (R3-verified version.)
// ---------------------------------------------------------------------------
#define OBM 64
#define OBN 128

__global__ __launch_bounds__(256) void gemm_out(
    const unsigned short* __restrict__ A, const unsigned short* __restrict__ Bt,
    const float* __restrict__ bias, float* __restrict__ Cout)
{
    const int N = 1024, Kd = 1024;
    __shared__ __align__(16) unsigned short As[OBM][GBK];
    __shared__ __align__(16) unsigned short Bs[OBN][GBK];

    const int tid = threadIdx.x;
    const int wave = tid >> 6, lane = tid & 63;
    const int quad = lane >> 4, cl = lane & 15;
    const int wm = (wave & 1) * 32, wn = (wave >> 1) * 64;
    const int bm = blockIdx.y * OBM, bn = blockIdx.x * OBN;

    const int ar = tid >> 2, ac = (tid & 3) * 8;
    const unsigned short* aS = A + (size_t)(bm + ar) * Kd + ac;
    const unsigned short* hS0 = Bt + (size_t)(bn + ar) * Kd + ac;
    const unsigned short* hS1 = hS0 + (size_t)64 * Kd;
    unsigned short* aD  = &As[0][0] + wave * 512;
    unsigned short* hD0 = &Bs[0][0] + wave * 512;
    unsigned short* hD1 = hD0 + 2048;

    f32x4 acc[2][4];
    #pragma unroll
    for (int mi = 0; mi < 2; mi++)
        #pragma unroll
        for (int ni = 0; ni < 4; ni++)
            #pragma unroll
            for (int r = 0; r < 4; r++) acc[mi][ni][r] = 0.f;

    for (int k0 = 0; k0 < Kd; k0 += GBK) {
        __syncthreads();
        GLDS(aS, aD);
        GLDS(hS0, hD0); GLDS(hS1, hD1);
        aS += GBK; hS0 += GBK; hS1 += GBK;
        __syncthreads();

        bf16x8 af[2], bh[4];
        #pragma unroll
        for (int mi = 0; mi < 2; mi++)
            af[mi] = *(const bf16x8*)&As[wm + mi * 16 + cl][quad * 8];
        #pragma unroll
        for (int ni = 0; ni < 4; ni++)
            bh[ni] = *(const bf16x8*)&Bs[wn + ni * 16 + cl][quad * 8];
        #pragma unroll
        for (int mi = 0; mi < 2; mi++)
            #pragma unroll
            for (int ni = 0; ni < 4; ni++)
                acc[mi][ni] = __builtin_amdgcn_mfma_f32_16x16x32_bf16(
                    af[mi], bh[ni], acc[mi][ni], 0, 0, 0);
    }

    #pragma unroll
    for (int ni = 0; ni < 4; ni++) {
        const int coln = bn + wn + ni * 16 + cl;
        const float bs = bias[coln];
        #pragma unroll
        for (int mi = 0; mi < 2; mi++) {
            const int row0 = bm + wm + mi * 16 + quad * 4;
            #pragma unroll
            for (int r = 0; r < 4; r++)
                Cout[(size_t)(row0 + r) * N + coln] = acc[mi][ni][r] + bs;
        }
    }
}

// ---------------------------------------------------------------------------
extern "C" void kernel_launch(void* const* d_in, const int* in_sizes, int n_in,
                              void* d_out, int out_size, void* d_ws, size_t ws_size,
                              hipStream_t stream)
{
    const float* x        = (const float*)d_in[0];
    const float* Wq       = (const float*)d_in[1];
    const float* bq       = (const float*)d_in[2];
    const float* Wk       = (const float*)d_in[3];
    const float* Wv       = (const float*)d_in[4];
    const float* bv       = (const float*)d_in[5];
    const float* Wo       = (const float*)d_in[6];
    const float* bo       = (const float*)d_in[7];
    const float* pos_bias = (const float*)d_in[8];
    float* out = (float*)d_out;

    const size_t ELEMS  = (size_t)BATCH * S_LEN * D_MODEL;  // 4 Mi
    const size_t WELEMS = (size_t)D_MODEL * D_MODEL;        // 1 Mi
    unsigned short* xb     = (unsigned short*)d_ws;
    unsigned short* Wqkvt  = xb + ELEMS;                    // [3072][1024]
    unsigned short* Wot    = Wqkvt + 3 * WELEMS;
    unsigned short* QKV    = Wot + WELEMS;                  // Qb | Kb | VTb
    unsigned short* Qb     = QKV;
    unsigned short* Kb     = Qb + ELEMS;
    unsigned short* VTb    = Kb + ELEMS;                    // [B,H,HD,S]
    unsigned short* Ab     = VTb + ELEMS;                   // attn out bf16 [B,S,D]
    float* pb_t            = (float*)(Ab + ELEMS);          // [NH][4096]

    prep<<<6208, 256, 0, stream>>>(x, Wq, Wk, Wv, Wo, pos_bias,
                                   xb, Wqkvt, Wot, pb_t);

    gemm_qkv<<<dim3(3072 / GBN, 4096 / GBM), 256, 0, stream>>>(
        xb, Wqkvt, bq, bv, QKV);

    attn_mfma<<<dim3(512), 512, 0, stream>>>(
        Qb, Kb, VTb, pb_t, Ab);

    gemm_out<<<dim3(1024 / OBN, 4096 / OBM), 256, 0, stream>>>(
        Ab, Wot, bo, out);
}